// Round 8
// baseline (9817.733 us; speedup 1.0000x reference)
//
#include <hip/hip_runtime.h>

#define Hdim 200
#define NP   800
#define Tlen 100
#define BT   32          // batch rows per WG -> grid = 256 = 1 WG/CU
#define KB   7           // K blocks of 32 (200 -> 224 padded)
#define HS   232         // padded h row stride (ushorts)
#define NT   50          // 800/16 gate-col tiles (M dimension of Z^T)
#define THREADS 640      // 10 waves x 5 M-tiles each
#define CH   5           // M-tiles per wave
#define CHSTR (NT*64*8)  // ushorts per K-chunk (25600)
#define MATSZ (KB*CHSTR) // 179200 ushorts per packed matrix
#define SBUF  2560       // ushorts per stage buffer (5 tiles x 512)

// s_waitcnt immediates (gfx9 encoding): vm[3:0]|exp[6:4]|lgkm[11:8]|vm[15:14]
#define WAIT_VM0   0x0F70   // vmcnt(0),  lgkm/exp ignored-max
#define WAIT_VM5   0x0F75   // vmcnt(5)
#define WAIT_LGKM0 0xC07F   // lgkmcnt(0), vmcnt/exp ignored-max

typedef float f32x4 __attribute__((ext_vector_type(4)));
typedef short s16x8 __attribute__((ext_vector_type(8)));

__device__ __forceinline__ ushort f2bf(float f) {
    unsigned u = __float_as_uint(f);
    return (ushort)((u + 0x7fffu + ((u >> 16) & 1u)) >> 16);   // RTNE
}
__device__ __forceinline__ float bf2f(ushort s) {
    return __uint_as_float(((unsigned)s) << 16);
}
__device__ __forceinline__ float sigmoid_fast(float v) {
    return 1.0f / (1.0f + __expf(-v));
}
__device__ __forceinline__ float tanh_fast(float v) {
    return 2.0f / (1.0f + __expf(-2.0f * v)) - 1.0f;
}

// ---- pack 5 recurrent matrices [200][800] fp32 -> bf16 fragment layout ----
// slot (mi, kb, tile, lane, j) = W[k = kb*32 + (lane>>4)*8 + j][n' = tile*16 + (lane&15)]
// gate-interleaved cols: n' = unit*4 + gate -> src col = gate*200 + unit. k>=200 -> 0.
__global__ void pack_weights(const float* __restrict__ U0, const float* __restrict__ W1,
                             const float* __restrict__ U1, const float* __restrict__ W2,
                             const float* __restrict__ U2, ushort* __restrict__ dst) {
    int idx = blockIdx.x * blockDim.x + threadIdx.x;
    if (idx >= 5 * KB * NT * 64) return;
    int lane = idx & 63; int rest = idx >> 6;
    int nt = rest % NT; rest /= NT;
    int kb = rest % KB; int mi = rest / KB;
    const float* src = (mi == 0) ? U0 : (mi == 1) ? W1 : (mi == 2) ? U1 : (mi == 3) ? W2 : U2;
    int np = nt * 16 + (lane & 15);
    int ncol = (np & 3) * Hdim + (np >> 2);          // gate*200 + unit
    int k0 = kb * 32 + (lane >> 4) * 8;
    ushort v[8];
#pragma unroll
    for (int j = 0; j < 8; ++j) {
        int k = k0 + j;
        v[j] = (k < Hdim) ? f2bf(src[k * NP + ncol]) : (ushort)0;
    }
    uint4 o;
    o.x = (unsigned)v[0] | ((unsigned)v[1] << 16);
    o.y = (unsigned)v[2] | ((unsigned)v[3] << 16);
    o.z = (unsigned)v[4] | ((unsigned)v[5] << 16);
    o.w = (unsigned)v[6] | ((unsigned)v[7] << 16);
    ((uint4*)dst)[idx] = o;
}

// Issue 5 async DMAs: one K-chunk's 5 fragment tiles -> wave-private LDS buffer.
__device__ __forceinline__ void stage_chunk(const ushort* gp, ushort* dstbuf, int lane) {
#pragma unroll
    for (int mt = 0; mt < CH; ++mt) {
        __builtin_amdgcn_global_load_lds(
            (const __attribute__((address_space(1))) void*)(gp + (size_t)mt * 512 + lane * 8),
            (__attribute__((address_space(3))) void*)(dstbuf + mt * 512),
            16, 0, 0);
    }
}

// Region of NC K-chunks (NC=7: U only; NC=14: U then W), 2-deep DMA pipeline:
// buffers ping-pong; wait vmcnt(5) = oldest chunk landed while next stays in
// flight; stage c+2 into the just-consumed buffer after lgkmcnt(0) guard.
template<int NC>
__device__ __forceinline__ void gemm_region(f32x4 (&acc)[2][CH],
                                            const ushort* __restrict__ apU,
                                            const ushort* bU,
                                            const ushort* __restrict__ apW,
                                            const ushort* bW,
                                            ushort* sl, int lane) {
    stage_chunk(apU, sl, lane);
    if (NC > 1) stage_chunk(apU + CHSTR, sl + SBUF, lane);
#pragma unroll
    for (int c = 0; c < NC; ++c) {
        if (c + 1 < NC) __builtin_amdgcn_s_waitcnt(WAIT_VM5);   // chunk c landed
        else            __builtin_amdgcn_s_waitcnt(WAIT_VM0);   // last chunk
        const ushort* buf = sl + (c & 1) * SBUF;
        s16x8 frag[CH];
#pragma unroll
        for (int mt = 0; mt < CH; ++mt)
            frag[mt] = *(const s16x8*)(buf + mt * 512 + lane * 8);
        const ushort* b = (c < KB) ? (bU + c * 32) : (bW + (c - KB) * 32);
        s16x8 bh0 = *(const s16x8*)(b);
        s16x8 bh1 = *(const s16x8*)(b + 16 * HS);
#pragma unroll
        for (int mt = 0; mt < CH; ++mt) {
            acc[0][mt] = __builtin_amdgcn_mfma_f32_16x16x32_bf16(frag[mt], bh0, acc[0][mt], 0, 0, 0);
            acc[1][mt] = __builtin_amdgcn_mfma_f32_16x16x32_bf16(frag[mt], bh1, acc[1][mt], 0, 0, 0);
        }
        if (c + 2 < NC) {
            const int p = c + 2;
            __builtin_amdgcn_s_waitcnt(WAIT_LGKM0);   // frag ds_reads retired before overwrite
            stage_chunk((p < KB) ? (apU + (size_t)p * CHSTR)
                                 : (apW + (size_t)(p - KB) * CHSTR),
                        sl + (c & 1) * SBUF, lane);
        }
    }
}

// lane-local cell update: acc[nt][mt] regs r=0..3 are gates i,f,g,o of
// unit u=(ct0+mt)*4+q, batch n=nt*16+l15. Writes new h (bf16) in place.
__device__ __forceinline__ void gate_phase(f32x4 (&acc)[2][CH],
                                           float (&creg)[2][CH],
                                           ushort (*hbl)[HS],
                                           int lane, int ct0) {
    const int l15 = lane & 15, q = lane >> 4;
#pragma unroll
    for (int nt = 0; nt < 2; ++nt) {
#pragma unroll
        for (int mt = 0; mt < CH; ++mt) {
            const int u = (ct0 + mt) * 4 + q;
            const int n = nt * 16 + l15;
            f32x4 z = acc[nt][mt];
            float iv = sigmoid_fast(z[0]);
            float fv = sigmoid_fast(z[1]);
            float gv = tanh_fast(z[2]);
            float ov = sigmoid_fast(z[3]);
            float c = fv * creg[nt][mt] + iv * gv;
            creg[nt][mt] = c;
            hbl[n][u] = f2bf(ov * tanh_fast(c));
        }
    }
}

__global__ void __launch_bounds__(THREADS)
lstm3_mfma(const float* __restrict__ x,
           const float* __restrict__ W0, const float* __restrict__ b0,
           const float* __restrict__ b1, const float* __restrict__ b2,
           const float* __restrict__ Wfc, const float* __restrict__ bfc,
           const ushort* __restrict__ packed,
           float* __restrict__ out) {
    __shared__ ushort hb[3][BT][HS];         // h state, bf16 (44.5 KB)
    __shared__ ushort stage[10][2][SBUF];    // 2-deep wave-private DMA staging (100 KB)
    __shared__ float  pbw[4][NP];            // permuted b0,b1,b2,W0 (12.8 KB)

    const int tid = threadIdx.x;
    const int wave = tid >> 6, lane = tid & 63;
    const int l15 = lane & 15, q = lane >> 4;
    const int ct0 = wave * CH;               // M-tile base
    const int bbase = blockIdx.x * BT;

    for (int i = tid; i < 3 * BT * HS; i += THREADS) ((ushort*)hb)[i] = 0;
    for (int i = tid; i < NP; i += THREADS) {
        int nc = (i & 3) * Hdim + (i >> 2);  // permuted col -> src col
        pbw[0][i] = b0[nc]; pbw[1][i] = b1[nc]; pbw[2][i] = b2[nc]; pbw[3][i] = W0[nc];
    }
    __syncthreads();

    float creg[3][2][CH];   // c state: 30 regs, static mapping
#pragma unroll
    for (int l = 0; l < 3; ++l)
#pragma unroll
        for (int nt = 0; nt < 2; ++nt)
#pragma unroll
            for (int mt = 0; mt < CH; ++mt) creg[l][nt][mt] = 0.0f;

    const size_t fragoff = (size_t)(ct0 * 64) * 8;   // lane offset added in DMA
    const ushort* pU0 = packed + fragoff;
    const ushort* pW1 = packed + (size_t)MATSZ + fragoff;
    const ushort* pU1 = packed + (size_t)2 * MATSZ + fragoff;
    const ushort* pW2 = packed + (size_t)3 * MATSZ + fragoff;
    const ushort* pU2 = packed + (size_t)4 * MATSZ + fragoff;
    const int bhoff = l15 * HS + q * 8;
    ushort* sl = &stage[wave][0][0];
    const float* xr0 = x + (size_t)(bbase + l15) * Tlen;        // per-lane x rows
    const float* xr1 = x + (size_t)(bbase + 16 + l15) * Tlen;

    for (int t = 0; t < Tlen; ++t) {
        f32x4 acc[2][CH];

        // ---- layer 0: Z^T = b0 + W0^T x_t + U0^T h0 ----
        const float xn0 = xr0[t];
        const float xn1 = xr1[t];
#pragma unroll
        for (int mt = 0; mt < CH; ++mt) {
            const int row = (ct0 + mt) * 16 + q * 4;
            float4 bb = *(const float4*)&pbw[0][row];
            float4 ww = *(const float4*)&pbw[3][row];
            acc[0][mt][0] = fmaf(xn0, ww.x, bb.x); acc[1][mt][0] = fmaf(xn1, ww.x, bb.x);
            acc[0][mt][1] = fmaf(xn0, ww.y, bb.y); acc[1][mt][1] = fmaf(xn1, ww.y, bb.y);
            acc[0][mt][2] = fmaf(xn0, ww.z, bb.z); acc[1][mt][2] = fmaf(xn1, ww.z, bb.z);
            acc[0][mt][3] = fmaf(xn0, ww.w, bb.w); acc[1][mt][3] = fmaf(xn1, ww.w, bb.w);
        }
        gemm_region<KB>(acc, pU0, &hb[0][0][0] + bhoff,
                        pU0, &hb[0][0][0] + bhoff, sl, lane);
        __syncthreads();                             // all reads of old h0 done
        gate_phase(acc, creg[0], hb[0], lane, ct0);  // write new h0 in place
        __syncthreads();                             // new h0 visible

        // ---- layer 1: Z^T = b1 + U1^T h1 + W1^T h0new ----
#pragma unroll
        for (int mt = 0; mt < CH; ++mt) {
            const int row = (ct0 + mt) * 16 + q * 4;
            float4 bb = *(const float4*)&pbw[1][row];
            acc[0][mt][0] = bb.x; acc[1][mt][0] = bb.x;
            acc[0][mt][1] = bb.y; acc[1][mt][1] = bb.y;
            acc[0][mt][2] = bb.z; acc[1][mt][2] = bb.z;
            acc[0][mt][3] = bb.w; acc[1][mt][3] = bb.w;
        }
        gemm_region<2 * KB>(acc, pU1, &hb[1][0][0] + bhoff,
                            pW1, &hb[0][0][0] + bhoff, sl, lane);
        __syncthreads();
        gate_phase(acc, creg[1], hb[1], lane, ct0);
        __syncthreads();

        // ---- layer 2: Z^T = b2 + U2^T h2 + W2^T h1new ----
#pragma unroll
        for (int mt = 0; mt < CH; ++mt) {
            const int row = (ct0 + mt) * 16 + q * 4;
            float4 bb = *(const float4*)&pbw[2][row];
            acc[0][mt][0] = bb.x; acc[1][mt][0] = bb.x;
            acc[0][mt][1] = bb.y; acc[1][mt][1] = bb.y;
            acc[0][mt][2] = bb.z; acc[1][mt][2] = bb.z;
            acc[0][mt][3] = bb.w; acc[1][mt][3] = bb.w;
        }
        gemm_region<2 * KB>(acc, pU2, &hb[2][0][0] + bhoff,
                            pW2, &hb[1][0][0] + bhoff, sl, lane);
        __syncthreads();
        gate_phase(acc, creg[2], hb[2], lane, ct0);
        __syncthreads();
    }

    // ---- dense head: y = tanh(h2 @ Wfc + bfc); contiguous float4 stores ----
    for (int gidx = tid; gidx < BT * 100; gidx += THREADS) {
        int m = gidx / 100;
        int j4 = (gidx % 100) * 4;
        const ushort* h2 = &hb[2][m][0];
        float4 a4 = *(const float4*)(bfc + j4);
        float s0 = a4.x, s1 = a4.y, s2 = a4.z, s3 = a4.w;
        for (int k = 0; k < Hdim; ++k) {
            float hk = bf2f(h2[k]);
            float4 w4 = *(const float4*)(Wfc + (size_t)k * 400 + j4);
            s0 = fmaf(hk, w4.x, s0);
            s1 = fmaf(hk, w4.y, s1);
            s2 = fmaf(hk, w4.z, s2);
            s3 = fmaf(hk, w4.w, s3);
        }
        float4 o4;
        o4.x = tanh_fast(s0); o4.y = tanh_fast(s1);
        o4.z = tanh_fast(s2); o4.w = tanh_fast(s3);
        *(float4*)(out + (size_t)(bbase + m) * 400 + j4) = o4;
    }
}

extern "C" void kernel_launch(void* const* d_in, const int* in_sizes, int n_in,
                              void* d_out, int out_size, void* d_ws, size_t ws_size,
                              hipStream_t stream) {
    const float* x   = (const float*)d_in[0];
    const float* W0  = (const float*)d_in[1];
    const float* U0  = (const float*)d_in[2];
    const float* b0  = (const float*)d_in[3];
    const float* W1  = (const float*)d_in[4];
    const float* U1  = (const float*)d_in[5];
    const float* b1  = (const float*)d_in[6];
    const float* W2  = (const float*)d_in[7];
    const float* U2  = (const float*)d_in[8];
    const float* b2  = (const float*)d_in[9];
    const float* Wfc = (const float*)d_in[10];
    const float* bfc = (const float*)d_in[11];
    float* out = (float*)d_out;
    ushort* packed = (ushort*)d_ws;

    const int B = in_sizes[0] / Tlen;   // 8192
    const int pack_threads = 5 * KB * NT * 64;
    pack_weights<<<(pack_threads + 255) / 256, 256, 0, stream>>>(U0, W1, U1, W2, U2, packed);
    lstm3_mfma<<<B / BT, THREADS, 0, stream>>>(x, W0, b0, b1, b2, Wfc, bfc, packed, out);
}

// Round 9
// 2799.609 us; speedup vs baseline: 3.5068x; 3.5068x over previous
//
#include <hip/hip_runtime.h>

#define Hdim 200
#define NP   800
#define Tlen 100
#define BT   32          // batch rows per WG -> grid = 256 = 1 WG/CU
#define KB   7           // K blocks of 32 (200 -> 224 padded)
#define HS   232         // padded h row stride (ushorts)
#define NT   50          // 800/16 gate-col tiles
#define THREADS 640      // 10 waves x 5 M-tiles each
#define CH   5           // M-tiles per wave
#define CHSTR (NT*64*8)  // ushorts per K-chunk (25600)
#define MATSZ (KB*CHSTR) // 179200 ushorts per packed matrix
#define SBUF  2560       // ushorts per stage buffer (5 tiles x 512)

// s_waitcnt immediates: vm[3:0]|exp[6:4]|lgkm[11:8]|vm[15:14]
#define WAIT_VM0   0x0F70   // vmcnt(0)
#define WAIT_VM5   0x0F75   // vmcnt(5)
#define WAIT_LGKM0 0xC07F   // lgkmcnt(0)

typedef float f32x4 __attribute__((ext_vector_type(4)));
typedef short s16x8 __attribute__((ext_vector_type(8)));

__device__ __forceinline__ ushort f2bf(float f) {
    unsigned u = __float_as_uint(f);
    return (ushort)((u + 0x7fffu + ((u >> 16) & 1u)) >> 16);   // RTNE
}
__device__ __forceinline__ float bf2f(ushort s) {
    return __uint_as_float(((unsigned)s) << 16);
}
__device__ __forceinline__ float sigmoid_fast(float v) {
    return 1.0f / (1.0f + __expf(-v));
}
__device__ __forceinline__ float tanh_fast(float v) {
    return 2.0f / (1.0f + __expf(-2.0f * v)) - 1.0f;
}
// WG barrier WITHOUT vmcnt drain: LDS visibility needs lgkmcnt(0) only.
// Weight DMAs in flight target wave-private buffers -> safe across barrier.
__device__ __forceinline__ void wg_barrier() {
    asm volatile("" ::: "memory");
    __builtin_amdgcn_s_waitcnt(WAIT_LGKM0);
    __builtin_amdgcn_s_barrier();
    asm volatile("" ::: "memory");
}

// ---- pack 5 recurrent matrices [200][800] fp32 -> bf16 fragment layout ----
// order in d_ws: [U0, W1, U1, W2, U2]
__global__ void pack_weights(const float* __restrict__ U0, const float* __restrict__ W1,
                             const float* __restrict__ U1, const float* __restrict__ W2,
                             const float* __restrict__ U2, ushort* __restrict__ dst) {
    int idx = blockIdx.x * blockDim.x + threadIdx.x;
    if (idx >= 5 * KB * NT * 64) return;
    int lane = idx & 63; int rest = idx >> 6;
    int nt = rest % NT; rest /= NT;
    int kb = rest % KB; int mi = rest / KB;
    const float* src = (mi == 0) ? U0 : (mi == 1) ? W1 : (mi == 2) ? U1 : (mi == 3) ? W2 : U2;
    int np = nt * 16 + (lane & 15);
    int ncol = (np & 3) * Hdim + (np >> 2);          // gate*200 + unit
    int k0 = kb * 32 + (lane >> 4) * 8;
    ushort v[8];
#pragma unroll
    for (int j = 0; j < 8; ++j) {
        int k = k0 + j;
        v[j] = (k < Hdim) ? f2bf(src[k * NP + ncol]) : (ushort)0;
    }
    uint4 o;
    o.x = (unsigned)v[0] | ((unsigned)v[1] << 16);
    o.y = (unsigned)v[2] | ((unsigned)v[3] << 16);
    o.z = (unsigned)v[4] | ((unsigned)v[5] << 16);
    o.w = (unsigned)v[6] | ((unsigned)v[7] << 16);
    ((uint4*)dst)[idx] = o;
}

// 5 async DMAs: one K-chunk's 5 fragment tiles -> wave-private LDS buffer.
__device__ __forceinline__ void stage_chunk(const ushort* gp, ushort* dstbuf, int lane) {
#pragma unroll
    for (int mt = 0; mt < CH; ++mt) {
        __builtin_amdgcn_global_load_lds(
            (const __attribute__((address_space(1))) void*)(gp + (size_t)mt * 512 + lane * 8),
            (__attribute__((address_space(3))) void*)(dstbuf + mt * 512),
            16, 0, 0);
    }
}

__device__ __forceinline__ void unpack4(const ushort* p, float (&o)[4]) {
    uint2 u = *(const uint2*)p;
    o[0] = bf2f((ushort)(u.x));  o[1] = bf2f((ushort)(u.x >> 16));
    o[2] = bf2f((ushort)(u.y));  o[3] = bf2f((ushort)(u.y >> 16));
}

// lane-local cell update (unchanged from R8)
__device__ __forceinline__ void gate_phase(f32x4 (&acc)[2][CH],
                                           float (&creg)[2][CH],
                                           ushort* __restrict__ hbl,  // layer base in hb flat
                                           int lane, int ct0) {
    const int l15 = lane & 15, q = lane >> 4;
#pragma unroll
    for (int nt = 0; nt < 2; ++nt) {
#pragma unroll
        for (int mt = 0; mt < CH; ++mt) {
            const int u = (ct0 + mt) * 4 + q;
            const int n = nt * 16 + l15;
            f32x4 z = acc[nt][mt];
            float iv = sigmoid_fast(z[0]);
            float fv = sigmoid_fast(z[1]);
            float gv = tanh_fast(z[2]);
            float ov = sigmoid_fast(z[3]);
            float c = fv * creg[nt][mt] + iv * gv;
            creg[nt][mt] = c;
            hbl[n * HS + u] = f2bf(ov * tanh_fast(c));
        }
    }
}

__global__ void __launch_bounds__(THREADS)
lstm3_mfma(const float* __restrict__ x,
           const float* __restrict__ W0, const float* __restrict__ b0,
           const float* __restrict__ b1, const float* __restrict__ b2,
           const float* __restrict__ Wfc, const float* __restrict__ bfc,
           const ushort* __restrict__ packed,
           float* __restrict__ out) {
    __shared__ ushort hb[3][BT][HS];        // h state, bf16 (44.5 KB)
    __shared__ ushort stage[10][2][SBUF];   // 2-deep wave-private staging (100 KB)
    __shared__ ushort pbwb[4][NP];          // permuted b0,b1,b2,W0 as bf16 (6.4 KB)
    __shared__ ushort xTs[Tlen][BT];        // x transposed, bf16 (6.4 KB)
    __shared__ uint   gTab[35];             // rotated weight-chunk offsets (ushorts)
    __shared__ uint   bhTab[35];            // matching h-operand offsets (ushorts)

    const int tid = threadIdx.x;
    const int wave = tid >> 6, lane = tid & 63;
    const int l15 = lane & 15, q = lane >> 4;
    const int ct0 = wave * CH;
    const int bx = blockIdx.x;
    const int bbase = bx * BT;

    for (int i = tid; i < 3 * BT * HS; i += THREADS) ((ushort*)hb)[i] = 0;
    for (int i = tid; i < NP; i += THREADS) {
        int nc = (i & 3) * Hdim + (i >> 2);   // permuted col -> src col
        pbwb[0][i] = f2bf(b0[nc]); pbwb[1][i] = f2bf(b1[nc]);
        pbwb[2][i] = f2bf(b2[nc]); pbwb[3][i] = f2bf(W0[nc]);
    }
    for (int i = tid; i < BT * Tlen; i += THREADS) {
        int m = i / Tlen, tt = i % Tlen;
        xTs[tt][m] = f2bf(x[(size_t)(bbase + m) * Tlen + tt]);
    }
    // per-WG rotated chunk tables: slot s in [0,35) -> weight offset + h offset
    if (tid < 35) {
        int s = tid; uint goff, bhoff;
        if (s < 7) {                       // layer0: U0, B=h0
            int c = (s + bx) % 7;
            goff = 0u * MATSZ + c * CHSTR;           bhoff = 0u * BT * HS + c * 32;
        } else if (s < 21) {               // layer1: U1 (B=h1) then W1 (B=h0new), rotated
            int c = (s - 7 + bx) % 14;
            if (c < 7) { goff = 2u * MATSZ + c * CHSTR;       bhoff = 1u * BT * HS + c * 32; }
            else       { goff = 1u * MATSZ + (c - 7) * CHSTR; bhoff = 0u * BT * HS + (c - 7) * 32; }
        } else {                           // layer2: U2 (B=h2) then W2 (B=h1new), rotated
            int c = (s - 21 + bx * 5) % 14;
            if (c < 7) { goff = 4u * MATSZ + c * CHSTR;       bhoff = 2u * BT * HS + c * 32; }
            else       { goff = 3u * MATSZ + (c - 7) * CHSTR; bhoff = 1u * BT * HS + (c - 7) * 32; }
        }
        gTab[s] = goff; bhTab[s] = bhoff;
    }
    __syncthreads();

    float creg[3][2][CH];
#pragma unroll
    for (int l = 0; l < 3; ++l)
#pragma unroll
        for (int nt = 0; nt < 2; ++nt)
#pragma unroll
            for (int mt = 0; mt < CH; ++mt) creg[l][nt][mt] = 0.0f;

    const ushort* pk = packed + (size_t)(ct0 * 64) * 8;   // + wave tile offset
    ushort* sl = &stage[wave][0][0];
    ushort* hbflat = &hb[0][0][0];
    const int bhbase = l15 * HS + q * 8;

    // prologue: issue slots 0,1 (parities 0,1); steady 10 DMAs in flight forever
    stage_chunk(pk + gTab[0], sl, lane);
    stage_chunk(pk + gTab[1], sl + SBUF, lane);
    int isl = 2;   // next slot to issue (mod 35, step-periodic)

    for (int t = 0; t < Tlen; ++t) {
        f32x4 acc[2][CH];

        // ---- layer 0 acc init: b0 + W0^T x_t (bf16 LDS constants) ----
        const float xn0 = bf2f(xTs[t][l15]);
        const float xn1 = bf2f(xTs[t][16 + l15]);
#pragma unroll
        for (int mt = 0; mt < CH; ++mt) {
            const int row = (ct0 + mt) * 16 + q * 4;
            float bb[4], ww[4];
            unpack4(&pbwb[0][row], bb);
            unpack4(&pbwb[3][row], ww);
#pragma unroll
            for (int r = 0; r < 4; ++r) {
                acc[0][mt][r] = fmaf(xn0, ww[r], bb[r]);
                acc[1][mt][r] = fmaf(xn1, ww[r], bb[r]);
            }
        }

        // ---- region A: slots 0..6 (U0 x h0_old) ----
#pragma unroll 1
        for (int s = 0; s < 7; ++s) {
            __builtin_amdgcn_s_waitcnt(WAIT_VM5);
            ushort* buf = sl + ((t + s) & 1) * SBUF;
            s16x8 frag[CH];
#pragma unroll
            for (int mt = 0; mt < CH; ++mt)
                frag[mt] = *(const s16x8*)(buf + mt * 512 + lane * 8);
            const ushort* bp = hbflat + bhTab[s] + bhbase;
            s16x8 bh0 = *(const s16x8*)bp;
            s16x8 bh1 = *(const s16x8*)(bp + 16 * HS);
#pragma unroll
            for (int mt = 0; mt < CH; ++mt) {
                acc[0][mt] = __builtin_amdgcn_mfma_f32_16x16x32_bf16(frag[mt], bh0, acc[0][mt], 0, 0, 0);
                acc[1][mt] = __builtin_amdgcn_mfma_f32_16x16x32_bf16(frag[mt], bh1, acc[1][mt], 0, 0, 0);
            }
            __builtin_amdgcn_s_waitcnt(WAIT_LGKM0);
            stage_chunk(pk + gTab[isl], buf, lane);
            isl = (isl == 34) ? 0 : isl + 1;
        }
        wg_barrier();
        gate_phase(acc, creg[0], hbflat + 0 * BT * HS, lane, ct0);  // h0 in place
        wg_barrier();

        // ---- layer 1 acc init ----
#pragma unroll
        for (int mt = 0; mt < CH; ++mt) {
            const int row = (ct0 + mt) * 16 + q * 4;
            float bb[4];
            unpack4(&pbwb[1][row], bb);
#pragma unroll
            for (int r = 0; r < 4; ++r) { acc[0][mt][r] = bb[r]; acc[1][mt][r] = bb[r]; }
        }
        // ---- region B: slots 7..20 (U1 x h1_old, W1 x h0_new, rotated mix) ----
#pragma unroll 1
        for (int s = 7; s < 21; ++s) {
            __builtin_amdgcn_s_waitcnt(WAIT_VM5);
            ushort* buf = sl + ((t + s) & 1) * SBUF;
            s16x8 frag[CH];
#pragma unroll
            for (int mt = 0; mt < CH; ++mt)
                frag[mt] = *(const s16x8*)(buf + mt * 512 + lane * 8);
            const ushort* bp = hbflat + bhTab[s] + bhbase;
            s16x8 bh0 = *(const s16x8*)bp;
            s16x8 bh1 = *(const s16x8*)(bp + 16 * HS);
#pragma unroll
            for (int mt = 0; mt < CH; ++mt) {
                acc[0][mt] = __builtin_amdgcn_mfma_f32_16x16x32_bf16(frag[mt], bh0, acc[0][mt], 0, 0, 0);
                acc[1][mt] = __builtin_amdgcn_mfma_f32_16x16x32_bf16(frag[mt], bh1, acc[1][mt], 0, 0, 0);
            }
            __builtin_amdgcn_s_waitcnt(WAIT_LGKM0);
            stage_chunk(pk + gTab[isl], buf, lane);
            isl = (isl == 34) ? 0 : isl + 1;
        }
        wg_barrier();
        gate_phase(acc, creg[1], hbflat + 1 * BT * HS, lane, ct0);  // h1 in place
        wg_barrier();

        // ---- layer 2 acc init ----
#pragma unroll
        for (int mt = 0; mt < CH; ++mt) {
            const int row = (ct0 + mt) * 16 + q * 4;
            float bb[4];
            unpack4(&pbwb[2][row], bb);
#pragma unroll
            for (int r = 0; r < 4; ++r) { acc[0][mt][r] = bb[r]; acc[1][mt][r] = bb[r]; }
        }
        // ---- region C: slots 21..34 (U2 x h2_old, W2 x h1_new, rotated mix) ----
#pragma unroll 1
        for (int s = 21; s < 35; ++s) {
            __builtin_amdgcn_s_waitcnt(WAIT_VM5);
            ushort* buf = sl + ((t + s) & 1) * SBUF;
            s16x8 frag[CH];
#pragma unroll
            for (int mt = 0; mt < CH; ++mt)
                frag[mt] = *(const s16x8*)(buf + mt * 512 + lane * 8);
            const ushort* bp = hbflat + bhTab[s] + bhbase;
            s16x8 bh0 = *(const s16x8*)bp;
            s16x8 bh1 = *(const s16x8*)(bp + 16 * HS);
#pragma unroll
            for (int mt = 0; mt < CH; ++mt) {
                acc[0][mt] = __builtin_amdgcn_mfma_f32_16x16x32_bf16(frag[mt], bh0, acc[0][mt], 0, 0, 0);
                acc[1][mt] = __builtin_amdgcn_mfma_f32_16x16x32_bf16(frag[mt], bh1, acc[1][mt], 0, 0, 0);
            }
            __builtin_amdgcn_s_waitcnt(WAIT_LGKM0);
            stage_chunk(pk + gTab[isl], buf, lane);   // wraps into next step's slots
            isl = (isl == 34) ? 0 : isl + 1;
        }
        wg_barrier();
        gate_phase(acc, creg[2], hbflat + 2 * BT * HS, lane, ct0);  // h2 in place
        wg_barrier();
    }
    __syncthreads();   // full drain (absorbs the 2 wrap DMAs) + h2 visibility

    // ---- dense head: y = tanh(h2 @ Wfc + bfc) ----
    for (int gidx = tid; gidx < BT * 100; gidx += THREADS) {
        int m = gidx / 100;
        int j4 = (gidx % 100) * 4;
        const ushort* h2 = &hb[2][m][0];
        float4 a4 = *(const float4*)(bfc + j4);
        float s0 = a4.x, s1 = a4.y, s2 = a4.z, s3 = a4.w;
        for (int k = 0; k < Hdim; ++k) {
            float hk = bf2f(h2[k]);
            float4 w4 = *(const float4*)(Wfc + (size_t)k * 400 + j4);
            s0 = fmaf(hk, w4.x, s0);
            s1 = fmaf(hk, w4.y, s1);
            s2 = fmaf(hk, w4.z, s2);
            s3 = fmaf(hk, w4.w, s3);
        }
        float4 o4;
        o4.x = tanh_fast(s0); o4.y = tanh_fast(s1);
        o4.z = tanh_fast(s2); o4.w = tanh_fast(s3);
        *(float4*)(out + (size_t)(bbase + m) * 400 + j4) = o4;
    }
}

extern "C" void kernel_launch(void* const* d_in, const int* in_sizes, int n_in,
                              void* d_out, int out_size, void* d_ws, size_t ws_size,
                              hipStream_t stream) {
    const float* x   = (const float*)d_in[0];
    const float* W0  = (const float*)d_in[1];
    const float* U0  = (const float*)d_in[2];
    const float* b0  = (const float*)d_in[3];
    const float* W1  = (const float*)d_in[4];
    const float* U1  = (const float*)d_in[5];
    const float* b1  = (const float*)d_in[6];
    const float* W2  = (const float*)d_in[7];
    const float* U2  = (const float*)d_in[8];
    const float* b2  = (const float*)d_in[9];
    const float* Wfc = (const float*)d_in[10];
    const float* bfc = (const float*)d_in[11];
    float* out = (float*)d_out;
    ushort* packed = (ushort*)d_ws;

    const int B = in_sizes[0] / Tlen;   // 8192
    const int pack_threads = 5 * KB * NT * 64;
    pack_weights<<<(pack_threads + 255) / 256, 256, 0, stream>>>(U0, W1, U1, W2, U2, packed);
    lstm3_mfma<<<B / BT, THREADS, 0, stream>>>(x, W0, b0, b1, b2, Wfc, bfc, packed, out);
}